// Round 2
// baseline (352.386 us; speedup 1.0000x reference)
//
#include <hip/hip_runtime.h>
#include <hip/hip_bf16.h>

typedef __bf16 v8bf16 __attribute__((ext_vector_type(8)));
typedef float f32x4 __attribute__((ext_vector_type(4)));
typedef ushort ushort8_t __attribute__((ext_vector_type(8)));

#define NROW  16
#define D1    256

__device__ __forceinline__ ushort bf16_rne(float x) {
    unsigned u = __builtin_bit_cast(unsigned, x);
    unsigned r = u + 0x7FFFu + ((u >> 16) & 1u);
    return (ushort)(r >> 16);
}
__device__ __forceinline__ float bf16_to_f(ushort h) {
    unsigned u = ((unsigned)h) << 16;
    return __builtin_bit_cast(float, u);
}
__device__ __forceinline__ void split_hi_lo(float x, ushort& hi, ushort& lo) {
    hi = bf16_rne(x);
    float rem = x - bf16_to_f(hi);
    lo = bf16_rne(rem);
}
__device__ __forceinline__ float tanh_fast(float x) {
    float xc = fminf(15.f, fmaxf(-15.f, x));
    float e = __expf(2.f * xc);
    return (e - 1.f) / (e + 1.f);
}

// ---- P0: transpose/split weights.
// blocks 0..319: W_ext = [W_unmixed; W_2e] -> Wt[col][k0..319] hi/lo
// blocks 320..831: W_mixed -> Wmt[col][k0..511] hi/lo
__global__ __launch_bounds__(256) void wtrans(const float* __restrict__ Wu,
                                              const float* __restrict__ W2,
                                              const float* __restrict__ Wm,
                                              ushort* __restrict__ Wthi, ushort* __restrict__ Wtlo,
                                              ushort* __restrict__ Wmthi, ushort* __restrict__ Wmtlo) {
    int t = threadIdx.x;
    int bid = blockIdx.x;
    if (bid < 320) {
        int k = bid;
        float w = (k < 256) ? Wu[k * 256 + t] : W2[(k - 256) * 256 + t];
        ushort hi, lo; split_hi_lo(w, hi, lo);
        Wthi[t * 320 + k] = hi;
        Wtlo[t * 320 + k] = lo;
    } else {
        int k = bid - 320;
        float w = Wm[k * 256 + t];
        ushort hi, lo; split_hi_lo(w, hi, lo);
        Wmthi[t * 512 + k] = hi;
        Wmtlo[t * 512 + k] = lo;
    }
}

// ---- P1: per-spin means of in_1e (bf16 hi/lo) + rolled col-spin means of in_2e (bf16 hi/lo)
__global__ __launch_bounds__(256) void prep1(const float* __restrict__ in1e,
                                             const float* __restrict__ in2e,
                                             ushort* __restrict__ mhi, ushort* __restrict__ mlo,
                                             ushort* __restrict__ t2hi, ushort* __restrict__ t2lo) {
    __shared__ float4 red[4][64];
    int b = blockIdx.x;
    int t = threadIdx.x;
    const float4* in1e4 = (const float4*)in1e;
    const float4* in2e4 = (const float4*)in2e;

    // ---- in_2e: thread = (r, ch, d4); mean over 8 cols of column-spin `ch`
    {
        int d4 = t & 7, ch = (t >> 3) & 1, r = t >> 4;
        size_t base4 = ((size_t)(b * 16 + r) * 16 + ch * 8) * 8 + d4;
        float4 s = in2e4[base4];
#pragma unroll
        for (int c = 1; c < 8; c++) {
            float4 v = in2e4[base4 + (size_t)c * 8];
            s.x += v.x; s.y += v.y; s.z += v.z; s.w += v.w;
        }
        s.x *= 0.125f; s.y *= 0.125f; s.z *= 0.125f; s.w *= 0.125f;
        int off = ((ch ^ (r >> 3)) << 5) + d4 * 4;   // same-spin block first
        size_t dst = (size_t)(b * 16 + r) * 64 + off;
        ushort4 hv, lv;
        split_hi_lo(s.x, hv.x, lv.x); split_hi_lo(s.y, hv.y, lv.y);
        split_hi_lo(s.z, hv.z, lv.z); split_hi_lo(s.w, hv.w, lv.w);
        *(ushort4*)(t2hi + dst) = hv;
        *(ushort4*)(t2lo + dst) = lv;
    }

    // ---- in_1e means: thread = (quarter, col4); 4-row partial sums, LDS reduce
    {
        int col4 = t & 63, q = t >> 6;
        size_t base4 = (size_t)(b * 16 + q * 4) * 64 + col4;
        float4 s = in1e4[base4];
#pragma unroll
        for (int r = 1; r < 4; r++) {
            float4 v = in1e4[base4 + (size_t)r * 64];
            s.x += v.x; s.y += v.y; s.z += v.z; s.w += v.w;
        }
        red[q][col4] = s;
    }
    __syncthreads();
    if (t < 128) {
        int col4 = t & 63, half = t >> 6;   // half = spin
        float4 a = red[half * 2][col4], c = red[half * 2 + 1][col4];
        float4 m;
        m.x = (a.x + c.x) * 0.125f; m.y = (a.y + c.y) * 0.125f;
        m.z = (a.z + c.z) * 0.125f; m.w = (a.w + c.w) * 0.125f;
        ushort4 hv, lv;
        split_hi_lo(m.x, hv.x, lv.x); split_hi_lo(m.y, hv.y, lv.y);
        split_hi_lo(m.z, hv.z, lv.z); split_hi_lo(m.w, hv.w, lv.w);
        size_t dst = (size_t)b * 512 + half * 256 + col4 * 4;
        *(ushort4*)(mhi + dst) = hv;
        *(ushort4*)(mlo + dst) = lv;
    }
}

// ---- P2: mixed[b][s][c] = all_spins[b][s] @ W_mixed + bias  (split-bf16 MFMA, M=32/block)
__global__ __launch_bounds__(256) void prep2(const ushort* __restrict__ mhi,
                                             const ushort* __restrict__ mlo,
                                             const ushort* __restrict__ Wmthi,
                                             const ushort* __restrict__ Wmtlo,
                                             const float* __restrict__ bias,
                                             float* __restrict__ mixed) {
    __shared__ __align__(16) ushort Amh[32 * 512];
    __shared__ __align__(16) ushort Aml[32 * 512];
    int t = threadIdx.x;
    int lane = t & 63, w = t >> 6;
    int b0 = blockIdx.x * 16;

    // stage A: row m = bl*2+s; A[m][k] = means[b0+bl][s^(k>>8)][k&255]
#pragma unroll
    for (int i = 0; i < 16; i++) {
        int idx = i * 256 + t;            // ushort8 (16B) chunk id, 0..4095
        int off16 = idx & 31;             // 32 x 16B = 512B = half-K
        int seg = idx >> 5;               // 0..127
        int arr = seg >> 6;               // 0 = hi, 1 = lo
        int rs = seg & 63;
        int row = rs >> 1, half = rs & 1;
        const ushort* src = (arr ? mlo : mhi) +
            (size_t)(b0 + (row >> 1)) * 512 + ((row & 1) ^ half) * 256 + off16 * 8;
        ushort8_t v = *(const ushort8_t*)src;
        unsigned byte = (unsigned)(row * 1024 + half * 512 + off16 * 16);
        byte ^= (unsigned)((row & 7) << 4);
        *(ushort8_t*)((char*)(arr ? Aml : Amh) + byte) = v;
    }
    __syncthreads();

    f32x4 acc[2][4] = {};
    int lrow = lane & 15, lg = lane >> 4;

    for (int ks = 0; ks < 16; ks++) {
        int k = ks * 32 + lg * 8;
        v8bf16 ah[2], al[2];
#pragma unroll
        for (int rf = 0; rf < 2; rf++) {
            int row = rf * 16 + lrow;
            unsigned byte = (unsigned)(row * 1024 + k * 2) ^ (unsigned)((row & 7) << 4);
            ah[rf] = *(const v8bf16*)((char*)Amh + byte);
            al[rf] = *(const v8bf16*)((char*)Aml + byte);
        }
#pragma unroll
        for (int cf = 0; cf < 4; cf++) {
            int col = w * 64 + cf * 16 + lrow;
            v8bf16 bh = *(const v8bf16*)(Wmthi + (size_t)col * 512 + k);
            v8bf16 bl = *(const v8bf16*)(Wmtlo + (size_t)col * 512 + k);
#pragma unroll
            for (int rf = 0; rf < 2; rf++) {
                acc[rf][cf] = __builtin_amdgcn_mfma_f32_16x16x32_bf16(ah[rf], bh, acc[rf][cf], 0, 0, 0);
                acc[rf][cf] = __builtin_amdgcn_mfma_f32_16x16x32_bf16(ah[rf], bl, acc[rf][cf], 0, 0, 0);
                acc[rf][cf] = __builtin_amdgcn_mfma_f32_16x16x32_bf16(al[rf], bh, acc[rf][cf], 0, 0, 0);
            }
        }
    }

    // epilogue: + bias (folded here so main adds one term), store
#pragma unroll
    for (int rf = 0; rf < 2; rf++) {
#pragma unroll
        for (int cf = 0; cf < 4; cf++) {
            int col = w * 64 + cf * 16 + lrow;
            float bs = bias[col];
#pragma unroll
            for (int r = 0; r < 4; r++) {
                int row = rf * 16 + lg * 4 + r;
                int bl_ = row >> 1, s = row & 1;
                mixed[((size_t)(b0 + bl_) * 2 + s) * 256 + col] = acc[rf][cf][r] + bs;
            }
        }
    }
}

// ---- Main: out = tanh(A_ext @ W_ext + mixed') + in_1e, split-bf16 3-pass MFMA
__global__ __launch_bounds__(256) void main_gemm(const float* __restrict__ in1e,
                                                 const ushort* __restrict__ t2hi,
                                                 const ushort* __restrict__ t2lo,
                                                 const ushort* __restrict__ Wthi,
                                                 const ushort* __restrict__ Wtlo,
                                                 const float* __restrict__ mixed,
                                                 float* __restrict__ out) {
    __shared__ __align__(16) ushort Ahi[64 * 320];
    __shared__ __align__(16) ushort Alo[64 * 320];
    int t = threadIdx.x;
    int lane = t & 63, w = t >> 6;
    size_t row0 = (size_t)blockIdx.x * 64;

    // stage in_1e (fp32 -> bf16 hi/lo), K = 0..255
#pragma unroll
    for (int i = 0; i < 16; i++) {
        int idx = i * 256 + t;     // float4 id
        int row = idx >> 6, c4 = idx & 63;
        float4 v = *(const float4*)(in1e + (row0 + row) * 256 + c4 * 4);
        ushort4 hv, lv;
        split_hi_lo(v.x, hv.x, lv.x); split_hi_lo(v.y, hv.y, lv.y);
        split_hi_lo(v.z, hv.z, lv.z); split_hi_lo(v.w, hv.w, lv.w);
        unsigned byte = (unsigned)(row * 640 + c4 * 8);
        byte ^= (unsigned)((row & 7) << 4);
        *(ushort4*)((char*)Ahi + byte) = hv;
        *(ushort4*)((char*)Alo + byte) = lv;
    }
    // stage t2cat (already bf16 hi/lo), K = 256..319
#pragma unroll
    for (int i = 0; i < 4; i++) {
        int idx = i * 256 + t;     // ushort4 id
        int row = idx >> 4, c4 = idx & 15;
        ushort4 hv = *(const ushort4*)(t2hi + (row0 + row) * 64 + c4 * 4);
        ushort4 lv = *(const ushort4*)(t2lo + (row0 + row) * 64 + c4 * 4);
        unsigned byte = (unsigned)(row * 640 + 512 + c4 * 8);
        byte ^= (unsigned)((row & 7) << 4);
        *(ushort4*)((char*)Ahi + byte) = hv;
        *(ushort4*)((char*)Alo + byte) = lv;
    }
    __syncthreads();

    f32x4 acc[4][4] = {};
    int lrow = lane & 15, lg = lane >> 4;

    for (int ks = 0; ks < 10; ks++) {
        int kk = ks * 32;
        v8bf16 ah[4], al[4];
#pragma unroll
        for (int rf = 0; rf < 4; rf++) {
            int row = rf * 16 + lrow;
            unsigned byte = (unsigned)(row * 640 + (kk + lg * 8) * 2);
            byte ^= (unsigned)((row & 7) << 4);
            ah[rf] = *(const v8bf16*)((char*)Ahi + byte);
            al[rf] = *(const v8bf16*)((char*)Alo + byte);
        }
#pragma unroll
        for (int cf = 0; cf < 4; cf++) {
            int col = w * 64 + cf * 16 + lrow;
            v8bf16 bh = *(const v8bf16*)(Wthi + (size_t)col * 320 + kk + lg * 8);
            v8bf16 bl = *(const v8bf16*)(Wtlo + (size_t)col * 320 + kk + lg * 8);
#pragma unroll
            for (int rf = 0; rf < 4; rf++) {
                acc[rf][cf] = __builtin_amdgcn_mfma_f32_16x16x32_bf16(ah[rf], bh, acc[rf][cf], 0, 0, 0);
                acc[rf][cf] = __builtin_amdgcn_mfma_f32_16x16x32_bf16(ah[rf], bl, acc[rf][cf], 0, 0, 0);
                acc[rf][cf] = __builtin_amdgcn_mfma_f32_16x16x32_bf16(al[rf], bh, acc[rf][cf], 0, 0, 0);
            }
        }
    }

    // epilogue: + mixed' (bias folded), tanh, + skip (reconstructed from LDS hi+lo)
#pragma unroll
    for (int rf = 0; rf < 4; rf++) {
        // rows rf*16..rf*16+15 are exactly one batch (row0 is 64-aligned)
        size_t bI = (row0 + rf * 16) >> 4;
        int s = lg >> 1;                       // lg 0,1 -> rows 0..7 (spin0); lg 2,3 -> spin1
#pragma unroll
        for (int cf = 0; cf < 4; cf++) {
            int col = w * 64 + cf * 16 + lrow;
            float mx = mixed[(bI * 2 + s) * 256 + col];
            f32x4 a = acc[rf][cf];
#pragma unroll
            for (int r = 0; r < 4; r++) {
                int row = rf * 16 + lg * 4 + r;
                unsigned byte = (unsigned)(row * 640 + col * 2) ^ (unsigned)((row & 7) << 4);
                float rec = bf16_to_f(*(const ushort*)((const char*)Ahi + byte)) +
                            bf16_to_f(*(const ushort*)((const char*)Alo + byte));
                float pre = a[r] + mx;
                out[(row0 + row) * 256 + col] = tanh_fast(pre) + rec;
            }
        }
    }
}

extern "C" void kernel_launch(void* const* d_in, const int* in_sizes, int n_in,
                              void* d_out, int out_size, void* d_ws, size_t ws_size,
                              hipStream_t stream) {
    const float* in1e = (const float*)d_in[0];
    const float* in2e = (const float*)d_in[1];
    const float* Wu   = (const float*)d_in[2];
    const float* bu   = (const float*)d_in[3];
    const float* Wm   = (const float*)d_in[4];
    const float* W2   = (const float*)d_in[5];

    char* ws = (char*)d_ws;
    ushort* t2hi  = (ushort*)(ws);                       // 8,388,608
    ushort* t2lo  = (ushort*)(ws + 8388608);             // 8,388,608
    ushort* mhi   = (ushort*)(ws + 16777216);            // 4,194,304
    ushort* mlo   = (ushort*)(ws + 20971520);            // 4,194,304
    float*  mixed = (float*)(ws + 25165824);             // 8,388,608
    ushort* Wthi  = (ushort*)(ws + 33554432);            // 163,840
    ushort* Wtlo  = (ushort*)(ws + 33718272);            // 163,840
    ushort* Wmthi = (ushort*)(ws + 33882112);            // 262,144
    ushort* Wmtlo = (ushort*)(ws + 34144256);            // 262,144
    float* out = (float*)d_out;

    wtrans<<<dim3(832), dim3(256), 0, stream>>>(Wu, W2, Wm, Wthi, Wtlo, Wmthi, Wmtlo);
    prep1<<<dim3(4096), dim3(256), 0, stream>>>(in1e, in2e, mhi, mlo, t2hi, t2lo);
    prep2<<<dim3(256), dim3(256), 0, stream>>>(mhi, mlo, Wmthi, Wmtlo, bu, mixed);
    main_gemm<<<dim3(1024), dim3(256), 0, stream>>>(in1e, t2hi, t2lo, Wthi, Wtlo, mixed, out);
}

// Round 3
// 335.149 us; speedup vs baseline: 1.0514x; 1.0514x over previous
//
#include <hip/hip_runtime.h>
#include <hip/hip_bf16.h>

typedef __bf16 v8bf16 __attribute__((ext_vector_type(8)));
typedef float f32x4 __attribute__((ext_vector_type(4)));
typedef ushort ushort8_t __attribute__((ext_vector_type(8)));

__device__ __forceinline__ ushort bf16_rne(float x) {
    unsigned u = __builtin_bit_cast(unsigned, x);
    unsigned r = u + 0x7FFFu + ((u >> 16) & 1u);
    return (ushort)(r >> 16);
}
__device__ __forceinline__ float bf16_to_f(ushort h) {
    unsigned u = ((unsigned)h) << 16;
    return __builtin_bit_cast(float, u);
}
__device__ __forceinline__ void split_hi_lo(float x, ushort& hi, ushort& lo) {
    hi = bf16_rne(x);
    float rem = x - bf16_to_f(hi);
    lo = bf16_rne(rem);
}
__device__ __forceinline__ float tanh_fast(float x) {
    float xc = fminf(15.f, fmaxf(-15.f, x));
    float e = __expf(2.f * xc);
    return 1.f - 2.f * __builtin_amdgcn_rcpf(e + 1.f);
}

// ---- P1 (fused):
// blocks 0..4095: per-batch means of in_1e (bf16 hi/lo) + rolled col-spin means of in_2e
// blocks 4096..4415: W_ext = [W_unmixed; W_2e] -> Wb fragment-ordered hi/lo
// blocks 4416..4927: W_mixed -> Wmb fragment-ordered hi/lo
__global__ __launch_bounds__(256) void prep(const float* __restrict__ in1e,
                                            const float* __restrict__ in2e,
                                            const float* __restrict__ Wu,
                                            const float* __restrict__ W2,
                                            const float* __restrict__ Wm,
                                            ushort* __restrict__ mhi, ushort* __restrict__ mlo,
                                            ushort* __restrict__ t2hi, ushort* __restrict__ t2lo,
                                            ushort* __restrict__ Wbhi, ushort* __restrict__ Wblo,
                                            ushort* __restrict__ Wmbhi, ushort* __restrict__ Wmblo) {
    __shared__ float4 red[4][64];
    int bid = blockIdx.x;
    int t = threadIdx.x;

    if (bid >= 4096) {
        // ---- weight re-layout into MFMA B-fragment order:
        // idx = ((ks*16 + cb)*64 + lg*16 + lrow)*8 + e ; col = cb*16+lrow ; k = ks*32+lg*8+e
        int k; const float* src; ushort* dhi; ushort* dlo;
        if (bid < 4416) {
            k = bid - 4096;
            src = (k < 256) ? (Wu + k * 256) : (W2 + (k - 256) * 256);
            dhi = Wbhi; dlo = Wblo;
        } else {
            k = bid - 4416;
            src = Wm + k * 256;
            dhi = Wmbhi; dlo = Wmblo;
        }
        int ks = k >> 5, lg = (k >> 3) & 3, e = k & 7;
        float w = src[t];
        int cb = t >> 4, lrow = t & 15;
        int idx = (ks * 16 + cb) * 512 + (lg * 16 + lrow) * 8 + e;
        ushort hi, lo; split_hi_lo(w, hi, lo);
        dhi[idx] = hi;
        dlo[idx] = lo;
        return;
    }

    int b = bid;
    const float4* in1e4 = (const float4*)in1e;
    const float4* in2e4 = (const float4*)in2e;

    // ---- in_2e: thread = (r, ch, d4); mean over 8 cols of column-spin `ch`
    {
        int d4 = t & 7, ch = (t >> 3) & 1, r = t >> 4;
        size_t base4 = ((size_t)(b * 16 + r) * 16 + ch * 8) * 8 + d4;
        float4 s = in2e4[base4];
#pragma unroll
        for (int c = 1; c < 8; c++) {
            float4 v = in2e4[base4 + (size_t)c * 8];
            s.x += v.x; s.y += v.y; s.z += v.z; s.w += v.w;
        }
        s.x *= 0.125f; s.y *= 0.125f; s.z *= 0.125f; s.w *= 0.125f;
        int off = ((ch ^ (r >> 3)) << 5) + d4 * 4;   // same-spin block first
        size_t dst = (size_t)(b * 16 + r) * 64 + off;
        ushort4 hv, lv;
        split_hi_lo(s.x, hv.x, lv.x); split_hi_lo(s.y, hv.y, lv.y);
        split_hi_lo(s.z, hv.z, lv.z); split_hi_lo(s.w, hv.w, lv.w);
        *(ushort4*)(t2hi + dst) = hv;
        *(ushort4*)(t2lo + dst) = lv;
    }

    // ---- in_1e means: thread = (quarter, col4); 4-row partial sums, LDS reduce
    {
        int col4 = t & 63, q = t >> 6;
        size_t base4 = (size_t)(b * 16 + q * 4) * 64 + col4;
        float4 s = in1e4[base4];
#pragma unroll
        for (int r = 1; r < 4; r++) {
            float4 v = in1e4[base4 + (size_t)r * 64];
            s.x += v.x; s.y += v.y; s.z += v.z; s.w += v.w;
        }
        red[q][col4] = s;
    }
    __syncthreads();
    if (t < 128) {
        int col4 = t & 63, half = t >> 6;   // half = spin
        float4 a = red[half * 2][col4], c = red[half * 2 + 1][col4];
        float4 m;
        m.x = (a.x + c.x) * 0.125f; m.y = (a.y + c.y) * 0.125f;
        m.z = (a.z + c.z) * 0.125f; m.w = (a.w + c.w) * 0.125f;
        ushort4 hv, lv;
        split_hi_lo(m.x, hv.x, lv.x); split_hi_lo(m.y, hv.y, lv.y);
        split_hi_lo(m.z, hv.z, lv.z); split_hi_lo(m.w, hv.w, lv.w);
        size_t dst = (size_t)b * 512 + half * 256 + col4 * 4;
        *(ushort4*)(mhi + dst) = hv;
        *(ushort4*)(mlo + dst) = lv;
    }
}

// ---- P2: mixed[b][s][c] = all_spins[b][s] @ W_mixed + bias  (split-bf16 MFMA, M=32/block)
__global__ __launch_bounds__(256) void prep2(const ushort* __restrict__ mhi,
                                             const ushort* __restrict__ mlo,
                                             const ushort* __restrict__ Wmbhi,
                                             const ushort* __restrict__ Wmblo,
                                             const float* __restrict__ bias,
                                             float* __restrict__ mixed) {
    __shared__ __align__(16) ushort Amh[32 * 512];
    __shared__ __align__(16) ushort Aml[32 * 512];
    int t = threadIdx.x;
    int lane = t & 63, w = t >> 6;
    int b0 = blockIdx.x * 16;

    // stage A: row m = bl*2+s; A[m][k] = means[b0+bl][s^(k>>8)][k&255]
#pragma unroll
    for (int i = 0; i < 16; i++) {
        int idx = i * 256 + t;            // ushort8 (16B) chunk id, 0..4095
        int off16 = idx & 31;             // 32 x 16B = 512B = half-K
        int seg = idx >> 5;               // 0..127
        int arr = seg >> 6;               // 0 = hi, 1 = lo
        int rs = seg & 63;
        int row = rs >> 1, half = rs & 1;
        const ushort* src = (arr ? mlo : mhi) +
            (size_t)(b0 + (row >> 1)) * 512 + ((row & 1) ^ half) * 256 + off16 * 8;
        ushort8_t v = *(const ushort8_t*)src;
        unsigned byte = (unsigned)(row * 1024 + half * 512 + off16 * 16);
        byte ^= (unsigned)((row & 7) << 4);
        *(ushort8_t*)((char*)(arr ? Aml : Amh) + byte) = v;
    }
    __syncthreads();

    f32x4 acc[2][4] = {};
    int lrow = lane & 15, lg = lane >> 4;

    for (int ks = 0; ks < 16; ks++) {
        int k = ks * 32 + lg * 8;
        v8bf16 ah[2], al[2];
#pragma unroll
        for (int rf = 0; rf < 2; rf++) {
            int row = rf * 16 + lrow;
            unsigned byte = (unsigned)(row * 1024 + k * 2) ^ (unsigned)((row & 7) << 4);
            ah[rf] = *(const v8bf16*)((char*)Amh + byte);
            al[rf] = *(const v8bf16*)((char*)Aml + byte);
        }
#pragma unroll
        for (int cf = 0; cf < 4; cf++) {
            int bidx = (ks * 16 + w * 4 + cf) * 512 + lane * 8;   // coalesced fragment order
            v8bf16 bh = *(const v8bf16*)(Wmbhi + bidx);
            v8bf16 bl = *(const v8bf16*)(Wmblo + bidx);
#pragma unroll
            for (int rf = 0; rf < 2; rf++) {
                acc[rf][cf] = __builtin_amdgcn_mfma_f32_16x16x32_bf16(ah[rf], bh, acc[rf][cf], 0, 0, 0);
                acc[rf][cf] = __builtin_amdgcn_mfma_f32_16x16x32_bf16(ah[rf], bl, acc[rf][cf], 0, 0, 0);
                acc[rf][cf] = __builtin_amdgcn_mfma_f32_16x16x32_bf16(al[rf], bh, acc[rf][cf], 0, 0, 0);
            }
        }
    }

    // epilogue: + bias (folded here so main adds one term), store
#pragma unroll
    for (int rf = 0; rf < 2; rf++) {
#pragma unroll
        for (int cf = 0; cf < 4; cf++) {
            int col = w * 64 + cf * 16 + lrow;
            float bs = bias[col];
#pragma unroll
            for (int r = 0; r < 4; r++) {
                int row = rf * 16 + lg * 4 + r;
                int bl_ = row >> 1, s = row & 1;
                mixed[((size_t)(b0 + bl_) * 2 + s) * 256 + col] = acc[rf][cf][r] + bs;
            }
        }
    }
}

// ---- Main: out = tanh(A_ext @ W_ext + mixed') + in_1e, split-bf16 3-pass MFMA
__global__ __launch_bounds__(256) void main_gemm(const float* __restrict__ in1e,
                                                 const ushort* __restrict__ t2hi,
                                                 const ushort* __restrict__ t2lo,
                                                 const ushort* __restrict__ Wbhi,
                                                 const ushort* __restrict__ Wblo,
                                                 const float* __restrict__ mixed,
                                                 float* __restrict__ out) {
    __shared__ __align__(16) ushort Ahi[64 * 320];
    __shared__ __align__(16) ushort Alo[64 * 320];
    int t = threadIdx.x;
    int lane = t & 63, w = t >> 6;
    size_t row0 = (size_t)blockIdx.x * 64;

    // stage in_1e (fp32 -> bf16 hi/lo), K = 0..255
#pragma unroll
    for (int i = 0; i < 16; i++) {
        int idx = i * 256 + t;     // float4 id
        int row = idx >> 6, c4 = idx & 63;
        float4 v = *(const float4*)(in1e + (row0 + row) * 256 + c4 * 4);
        ushort4 hv, lv;
        split_hi_lo(v.x, hv.x, lv.x); split_hi_lo(v.y, hv.y, lv.y);
        split_hi_lo(v.z, hv.z, lv.z); split_hi_lo(v.w, hv.w, lv.w);
        unsigned byte = (unsigned)(row * 640 + c4 * 8);
        byte ^= (unsigned)((row & 7) << 4);
        *(ushort4*)((char*)Ahi + byte) = hv;
        *(ushort4*)((char*)Alo + byte) = lv;
    }
    // stage t2cat (already bf16 hi/lo), K = 256..319
#pragma unroll
    for (int i = 0; i < 4; i++) {
        int idx = i * 256 + t;     // ushort4 id
        int row = idx >> 4, c4 = idx & 15;
        ushort4 hv = *(const ushort4*)(t2hi + (row0 + row) * 64 + c4 * 4);
        ushort4 lv = *(const ushort4*)(t2lo + (row0 + row) * 64 + c4 * 4);
        unsigned byte = (unsigned)(row * 640 + 512 + c4 * 8);
        byte ^= (unsigned)((row & 7) << 4);
        *(ushort4*)((char*)Ahi + byte) = hv;
        *(ushort4*)((char*)Alo + byte) = lv;
    }
    __syncthreads();

    f32x4 acc[4][4] = {};
    int lrow = lane & 15, lg = lane >> 4;

    for (int ks = 0; ks < 10; ks++) {
        int kk = ks * 32;
        v8bf16 ah[4], al[4];
#pragma unroll
        for (int rf = 0; rf < 4; rf++) {
            int row = rf * 16 + lrow;
            unsigned byte = (unsigned)(row * 640 + (kk + lg * 8) * 2);
            byte ^= (unsigned)((row & 7) << 4);
            ah[rf] = *(const v8bf16*)((char*)Ahi + byte);
            al[rf] = *(const v8bf16*)((char*)Alo + byte);
        }
#pragma unroll
        for (int cf = 0; cf < 4; cf++) {
            int bidx = (ks * 16 + w * 4 + cf) * 512 + lane * 8;   // coalesced fragment order
            v8bf16 bh = *(const v8bf16*)(Wbhi + bidx);
            v8bf16 bl = *(const v8bf16*)(Wblo + bidx);
#pragma unroll
            for (int rf = 0; rf < 4; rf++) {
                acc[rf][cf] = __builtin_amdgcn_mfma_f32_16x16x32_bf16(ah[rf], bh, acc[rf][cf], 0, 0, 0);
                acc[rf][cf] = __builtin_amdgcn_mfma_f32_16x16x32_bf16(ah[rf], bl, acc[rf][cf], 0, 0, 0);
                acc[rf][cf] = __builtin_amdgcn_mfma_f32_16x16x32_bf16(al[rf], bh, acc[rf][cf], 0, 0, 0);
            }
        }
    }

    // epilogue: + mixed' (bias folded), tanh, + skip (reconstructed from LDS hi+lo)
#pragma unroll
    for (int rf = 0; rf < 4; rf++) {
        // rows rf*16..rf*16+15 are exactly one batch (row0 is 64-aligned)
        size_t bI = (row0 + rf * 16) >> 4;
        int s = lg >> 1;                       // lg 0,1 -> rows 0..7 (spin0); lg 2,3 -> spin1
#pragma unroll
        for (int cf = 0; cf < 4; cf++) {
            int col = w * 64 + cf * 16 + lrow;
            float mx = mixed[(bI * 2 + s) * 256 + col];
            f32x4 a = acc[rf][cf];
#pragma unroll
            for (int r = 0; r < 4; r++) {
                int row = rf * 16 + lg * 4 + r;
                unsigned byte = (unsigned)(row * 640 + col * 2) ^ (unsigned)((row & 7) << 4);
                float rec = bf16_to_f(*(const ushort*)((const char*)Ahi + byte)) +
                            bf16_to_f(*(const ushort*)((const char*)Alo + byte));
                float pre = a[r] + mx;
                out[(row0 + row) * 256 + col] = tanh_fast(pre) + rec;
            }
        }
    }
}

extern "C" void kernel_launch(void* const* d_in, const int* in_sizes, int n_in,
                              void* d_out, int out_size, void* d_ws, size_t ws_size,
                              hipStream_t stream) {
    const float* in1e = (const float*)d_in[0];
    const float* in2e = (const float*)d_in[1];
    const float* Wu   = (const float*)d_in[2];
    const float* bu   = (const float*)d_in[3];
    const float* Wm   = (const float*)d_in[4];
    const float* W2   = (const float*)d_in[5];

    char* ws = (char*)d_ws;
    ushort* t2hi  = (ushort*)(ws);                       // 8,388,608
    ushort* t2lo  = (ushort*)(ws + 8388608);             // 8,388,608
    ushort* mhi   = (ushort*)(ws + 16777216);            // 4,194,304
    ushort* mlo   = (ushort*)(ws + 20971520);            // 4,194,304
    float*  mixed = (float*)(ws + 25165824);             // 8,388,608
    ushort* Wbhi  = (ushort*)(ws + 33554432);            // 163,840
    ushort* Wblo  = (ushort*)(ws + 33718272);            // 163,840
    ushort* Wmbhi = (ushort*)(ws + 33882112);            // 262,144
    ushort* Wmblo = (ushort*)(ws + 34144256);            // 262,144
    float* out = (float*)d_out;

    prep<<<dim3(4928), dim3(256), 0, stream>>>(in1e, in2e, Wu, W2, Wm,
                                               mhi, mlo, t2hi, t2lo,
                                               Wbhi, Wblo, Wmbhi, Wmblo);
    prep2<<<dim3(256), dim3(256), 0, stream>>>(mhi, mlo, Wmbhi, Wmblo, bu, mixed);
    main_gemm<<<dim3(1024), dim3(256), 0, stream>>>(in1e, t2hi, t2lo, Wbhi, Wblo, mixed, out);
}